// Round 2
// baseline (296.773 us; speedup 1.0000x reference)
//
#include <hip/hip_runtime.h>
#include <hip/hip_bf16.h>

// Problem: B=4, S=4096, D=1024, H=64 single attention head.
// inputs fp32: x[4,4096,1024], Wq[1024,64], bq[64], Wk, bk, Wv, bv
// output FP32: [4,4096,64]  (reference is pure fp32 jnp ops)

#define S_LEN 4096
#define D_MODEL 1024
#define NBATCH 4

typedef __attribute__((ext_vector_type(8))) short bf16x8;
typedef __attribute__((ext_vector_type(4))) float f32x4;

__device__ inline short f2bf(float f) {
    union { float f; unsigned u; } v;
    v.f = f;
    unsigned r = v.u + 0x7fffu + ((v.u >> 16) & 1u);  // RNE
    return (short)(r >> 16);
}

// ---------------- kernel 1: W -> Wt bf16 [192][1024] (transposed, concat Q|K|V)
__global__ void prep_w(const float* __restrict__ Wq, const float* __restrict__ Wk,
                       const float* __restrict__ Wv, short* __restrict__ Wt) {
    int idx = blockIdx.x * 256 + threadIdx.x;      // idx = n*1024 + k, n in [0,192)
    int n = idx >> 10;
    int k = idx & 1023;
    const float* W = (n < 64) ? Wq : (n < 128 ? Wk : Wv);
    int h = n & 63;
    Wt[idx] = f2bf(W[k * 64 + h]);
}

// ---------------- kernel 2: QKV projection
// grid 512 x 128 threads (2 waves). Each wave: 16 rows x 192 cols, K=1024.
__launch_bounds__(128)
__global__ void proj_kernel(const float* __restrict__ x, const short* __restrict__ Wt,
                            const float* __restrict__ bq, const float* __restrict__ bk,
                            const float* __restrict__ bv,
                            short* __restrict__ Qb, short* __restrict__ Kb,
                            short* __restrict__ Vt) {
    int w = threadIdx.x >> 6;
    int lane = threadIdx.x & 63;
    int g = lane >> 4, ln = lane & 15;
    int rowbase = blockIdx.x * 32 + w * 16;        // 16 rows per wave
    int arow = rowbase + ln;                       // A-frag row (lane&15)

    f32x4 acc[12];
#pragma unroll
    for (int i = 0; i < 12; ++i) acc[i] = (f32x4){0.f, 0.f, 0.f, 0.f};

    const float* xp = x + (size_t)arow * D_MODEL + g * 8;
    const short* wp = Wt + (size_t)ln * D_MODEL + g * 8;

#pragma unroll 4
    for (int kk = 0; kk < 32; ++kk) {
        f32x4 a0 = *(const f32x4*)(xp + kk * 32);
        f32x4 a1 = *(const f32x4*)(xp + kk * 32 + 4);
        bf16x8 a;
#pragma unroll
        for (int j = 0; j < 4; ++j) a[j] = f2bf(a0[j]);
#pragma unroll
        for (int j = 0; j < 4; ++j) a[4 + j] = f2bf(a1[j]);
#pragma unroll
        for (int nt = 0; nt < 12; ++nt) {
            bf16x8 bfr = *(const bf16x8*)(wp + (size_t)nt * 16 * D_MODEL + kk * 32);
            acc[nt] = __builtin_amdgcn_mfma_f32_16x16x32_bf16(a, bfr, acc[nt], 0, 0, 0);
        }
    }

    // epilogue: +bias, write Q,K row-major bf16; V transposed bf16
#pragma unroll
    for (int nt = 0; nt < 12; ++nt) {
        int proj = nt >> 2;                 // 0=Q 1=K 2=V
        int h = (nt & 3) * 16 + ln;         // head col 0..63
        float bias = (proj == 0 ? bq : (proj == 1 ? bk : bv))[h];
#pragma unroll
        for (int r = 0; r < 4; ++r) {
            int srow = rowbase + g * 4 + r;     // global row = b*4096 + s
            float v = acc[nt][r] + bias;
            short hv = f2bf(v);
            if (proj == 0) {
                Qb[(size_t)srow * 64 + h] = hv;
            } else if (proj == 1) {
                Kb[(size_t)srow * 64 + h] = hv;
            } else {
                int b = srow >> 12, s = srow & 4095;
                Vt[((size_t)b * 64 + h) * S_LEN + s] = hv;
            }
        }
    }
}

// ---------------- kernel 3: flash attention
// grid 512 (= 4 batches * 128 q-tiles of 32 rows) x 128 threads (2 waves, 16 q-rows each)
__launch_bounds__(128)
__global__ void attn_kernel(const short* __restrict__ Qb, const short* __restrict__ Kb,
                            const short* __restrict__ Vt, float* __restrict__ out) {
    __shared__ short plds[2 * 16 * 64];            // per-wave 16x64 bf16 P tile (swizzled)
    int w = threadIdx.x >> 6;
    int lane = threadIdx.x & 63;
    int g = lane >> 4, ln = lane & 15;
    int blk = blockIdx.x;
    int b = blk >> 7;                              // 128 tiles per batch
    int qt = blk & 127;
    int qb = qt * 32 + w * 16;                     // q row base within batch

    const short* Kbase = Kb + (size_t)b * S_LEN * 64;
    const short* Vbase = Vt + (size_t)b * 64 * S_LEN;

    bf16x8 qa[2];
    {
        const short* qp = Qb + ((size_t)b * S_LEN + qb + ln) * 64 + g * 8;
        qa[0] = *(const bf16x8*)(qp);
        qa[1] = *(const bf16x8*)(qp + 32);
    }

    f32x4 oacc[4];
#pragma unroll
    for (int i = 0; i < 4; ++i) oacc[i] = (f32x4){0.f, 0.f, 0.f, 0.f};
    float m[4], l[4];
#pragma unroll
    for (int r = 0; r < 4; ++r) { m[r] = -1e30f; l[r] = 0.f; }

    char* myp = (char*)(plds + w * 1024);          // 2KB region, wave-private
    const float CEXP = 0.18033688011112042f;       // log2(e) / sqrt(64)

    const short* kp = Kbase + (size_t)ln * 64 + g * 8;
    const short* vp = Vbase + (size_t)ln * S_LEN + g * 8;

    for (int t = 0; t < 64; ++t) {
        // ---- S = Q K^T  (16 q-rows x 64 k-cols)
        f32x4 sacc[4];
#pragma unroll
        for (int i = 0; i < 4; ++i) sacc[i] = (f32x4){0.f, 0.f, 0.f, 0.f};
#pragma unroll
        for (int hh = 0; hh < 2; ++hh) {
#pragma unroll
            for (int kt = 0; kt < 4; ++kt) {
                bf16x8 kb = *(const bf16x8*)(kp + (size_t)(t * 64 + kt * 16) * 64 + hh * 32);
                sacc[kt] = __builtin_amdgcn_mfma_f32_16x16x32_bf16(qa[hh], kb, sacc[kt], 0, 0, 0);
            }
        }

        // ---- online softmax (rows = g*4+r, cols = kt*16 + ln)
        float fsc[4];
#pragma unroll
        for (int r = 0; r < 4; ++r) {
            float mx = fmaxf(fmaxf(sacc[0][r], sacc[1][r]), fmaxf(sacc[2][r], sacc[3][r]));
            mx = fmaxf(mx, __shfl_xor(mx, 1));
            mx = fmaxf(mx, __shfl_xor(mx, 2));
            mx = fmaxf(mx, __shfl_xor(mx, 4));
            mx = fmaxf(mx, __shfl_xor(mx, 8));
            float mn = fmaxf(m[r], mx);
            fsc[r] = exp2f((m[r] - mn) * CEXP);
            m[r] = mn;
        }
#pragma unroll
        for (int r = 0; r < 4; ++r) {
            int row = g * 4 + r;
            float s = 0.f;
#pragma unroll
            for (int kt = 0; kt < 4; ++kt) {
                float p = exp2f((sacc[kt][r] - m[r]) * CEXP);
                s += p;
                int byte = row * 128 + (((kt * 32) + ln * 2) ^ ((row & 7) << 4));
                *(short*)(myp + byte) = f2bf(p);
            }
            s += __shfl_xor(s, 1);
            s += __shfl_xor(s, 2);
            s += __shfl_xor(s, 4);
            s += __shfl_xor(s, 8);
            l[r] = l[r] * fsc[r] + s;
            oacc[0][r] *= fsc[r];
            oacc[1][r] *= fsc[r];
            oacc[2][r] *= fsc[r];
            oacc[3][r] *= fsc[r];
        }

        asm volatile("s_waitcnt lgkmcnt(0)" ::: "memory");

        // ---- A-fragments of P from LDS (row = ln, k = kk*32 + g*8 .. +7)
        bf16x8 pa[2];
#pragma unroll
        for (int kk = 0; kk < 2; ++kk) {
            int byte = ln * 128 + (((kk * 64) + g * 16) ^ ((ln & 7) << 4));
            pa[kk] = *(const bf16x8*)(myp + byte);
        }

        // ---- O += P V
#pragma unroll
        for (int nt = 0; nt < 4; ++nt) {
#pragma unroll
            for (int kk = 0; kk < 2; ++kk) {
                bf16x8 vb = *(const bf16x8*)(vp + (size_t)(nt * 16) * S_LEN + t * 64 + kk * 32);
                oacc[nt] = __builtin_amdgcn_mfma_f32_16x16x32_bf16(pa[kk], vb, oacc[nt], 0, 0, 0);
            }
        }
    }

    // ---- epilogue: O / l -> fp32 out
#pragma unroll
    for (int r = 0; r < 4; ++r) {
        float inv = 1.0f / l[r];
        size_t srow = (size_t)b * S_LEN + qb + g * 4 + r;
#pragma unroll
        for (int nt = 0; nt < 4; ++nt) {
            out[srow * 64 + nt * 16 + ln] = oacc[nt][r] * inv;
        }
    }
}

extern "C" void kernel_launch(void* const* d_in, const int* in_sizes, int n_in,
                              void* d_out, int out_size, void* d_ws, size_t ws_size,
                              hipStream_t stream) {
    const float* x  = (const float*)d_in[0];
    const float* Wq = (const float*)d_in[1];
    const float* bq = (const float*)d_in[2];
    const float* Wk = (const float*)d_in[3];
    const float* bk = (const float*)d_in[4];
    const float* Wv = (const float*)d_in[5];
    const float* bv = (const float*)d_in[6];

    short* ws = (short*)d_ws;
    short* Wt = ws;                       // 192*1024
    short* Qb = Wt + 192 * 1024;          // 16384*64
    short* Kb = Qb + 16384 * 64;
    short* Vt = Kb + 16384 * 64;          // transposed per batch [64][4096]

    prep_w<<<768, 256, 0, stream>>>(Wq, Wk, Wv, Wt);
    proj_kernel<<<512, 128, 0, stream>>>(x, Wt, bq, bk, bv, Qb, Kb, Vt);
    attn_kernel<<<512, 128, 0, stream>>>(Qb, Kb, Vt, (float*)d_out);
}

// Round 3
// 180.989 us; speedup vs baseline: 1.6397x; 1.6397x over previous
//
#include <hip/hip_runtime.h>
#include <hip/hip_bf16.h>

// B=4, S=4096, D=1024, H=64 single attention head.
// inputs fp32: x[4,4096,1024], Wq[1024,64], bq[64], Wk, bk, Wv, bv
// output fp32: [4,4096,64]

#define S_LEN 4096
#define D_MODEL 1024

typedef __attribute__((ext_vector_type(8))) short bf16x8;
typedef __attribute__((ext_vector_type(4))) float f32x4;

__device__ inline short f2bf(float f) {
    union { float f; unsigned u; } v;
    v.f = f;
    unsigned r = v.u + 0x7fffu + ((v.u >> 16) & 1u);  // RNE
    return (short)(r >> 16);
}

__device__ inline unsigned cvt_pk(float lo, float hi) {
    unsigned r;
    asm("v_cvt_pk_bf16_f32 %0, %1, %2" : "=v"(r) : "v"(lo), "v"(hi));
    return r;
}

// ---------------- kernel 1: W -> Wt bf16 [192][1024] (transposed, concat Q|K|V)
__global__ void prep_w(const float* __restrict__ Wq, const float* __restrict__ Wk,
                       const float* __restrict__ Wv, short* __restrict__ Wt) {
    int idx = blockIdx.x * 256 + threadIdx.x;
    int n = idx >> 10;
    int k = idx & 1023;
    const float* W = (n < 64) ? Wq : (n < 128 ? Wk : Wv);
    int h = n & 63;
    Wt[idx] = f2bf(W[k * 64 + h]);
}

// ---------------- kernel 2: QKV projection, 4-way split-K
// grid 512 x 512 threads (8 waves): wave = (rt = w&1 row-tile of 16, ks = w>>2.. see below)
// block covers 32 rows x full K=1024; wave (rt, ks) does rows rt*16.., K chunk ks*256..
__launch_bounds__(512, 4)
__global__ void proj_kernel(const float* __restrict__ x, const short* __restrict__ Wt,
                            const float* __restrict__ bq, const float* __restrict__ bk,
                            const float* __restrict__ bv,
                            short* __restrict__ Qb, short* __restrict__ Kb,
                            short* __restrict__ Vt) {
    __shared__ float psm[6 * 3264];                 // 6 staging regions (ks>0), 76.5 KB
    int w = threadIdx.x >> 6;
    int lane = threadIdx.x & 63;
    int g = lane >> 4, ln = lane & 15;
    int rt = w & 1, ks = w >> 1;                    // rt in {0,1}, ks in {0..3}
    int rowbase = blockIdx.x * 32 + rt * 16;

    f32x4 acc[12];
#pragma unroll
    for (int i = 0; i < 12; ++i) acc[i] = (f32x4){0.f, 0.f, 0.f, 0.f};

    const float* xp = x + (size_t)(rowbase + ln) * D_MODEL + ks * 256 + g * 8;
    const short* wp = Wt + (size_t)ln * D_MODEL + ks * 256 + g * 8;

#pragma unroll 2
    for (int kk = 0; kk < 8; ++kk) {
        f32x4 a0 = *(const f32x4*)(xp + kk * 32);
        f32x4 a1 = *(const f32x4*)(xp + kk * 32 + 4);
        union { bf16x8 v; unsigned u[4]; } A;
        A.u[0] = cvt_pk(a0[0], a0[1]);
        A.u[1] = cvt_pk(a0[2], a0[3]);
        A.u[2] = cvt_pk(a1[0], a1[1]);
        A.u[3] = cvt_pk(a1[2], a1[3]);
#pragma unroll
        for (int nt = 0; nt < 12; ++nt) {
            bf16x8 bfr = *(const bf16x8*)(wp + (size_t)nt * 16 * D_MODEL + kk * 32);
            acc[nt] = __builtin_amdgcn_mfma_f32_16x16x32_bf16(A.v, bfr, acc[nt], 0, 0, 0);
        }
    }

    if (ks > 0) {
        float* st = psm + ((ks - 1) * 2 + rt) * 3264;
#pragma unroll
        for (int nt = 0; nt < 12; ++nt)
#pragma unroll
            for (int r = 0; r < 4; ++r)
                st[nt * 272 + (g * 4 + r) * 17 + ln] = acc[nt][r];
    }
    __syncthreads();
    if (ks == 0) {
        const float* s0 = psm + (0 + rt) * 3264;
        const float* s1 = psm + (2 + rt) * 3264;
        const float* s2 = psm + (4 + rt) * 3264;
#pragma unroll
        for (int nt = 0; nt < 12; ++nt) {
            int proj = nt >> 2;
            int h = (nt & 3) * 16 + ln;
            float bias = (proj == 0 ? bq : (proj == 1 ? bk : bv))[h];
#pragma unroll
            for (int r = 0; r < 4; ++r) {
                int idx = nt * 272 + (g * 4 + r) * 17 + ln;
                float v = acc[nt][r] + s0[idx] + s1[idx] + s2[idx] + bias;
                short hv = f2bf(v);
                int srow = rowbase + g * 4 + r;
                if (proj == 0) {
                    Qb[(size_t)srow * 64 + h] = hv;
                } else if (proj == 1) {
                    Kb[(size_t)srow * 64 + h] = hv;
                } else {
                    int b = srow >> 12, s = srow & 4095;
                    Vt[((size_t)b * 64 + h) * S_LEN + s] = hv;
                }
            }
        }
    }
}

// ---------------- kernel 3: flash attention, 4-way split-S
// grid 1024 (4 batches x 256 q-tiles of 16) x 256 threads (4 waves).
// Wave w handles keys [w*1024, (w+1)*1024) in 16 tiles of 64; LDS merge at end.
__launch_bounds__(256, 4)
__global__ void attn_kernel(const short* __restrict__ Qb, const short* __restrict__ Kb,
                            const short* __restrict__ Vt, float* __restrict__ out) {
    __shared__ float smem[4 * 1088 + 128];          // olds[4][16][68] + ml[4][16][2]; P aliases first 8KB
    int w = threadIdx.x >> 6;
    int lane = threadIdx.x & 63;
    int g = lane >> 4, ln = lane & 15;
    int b = blockIdx.x >> 8;
    int qt = blockIdx.x & 255;

    const short* Kbase = Kb + (size_t)b * S_LEN * 64;
    const short* Vbase = Vt + (size_t)b * 64 * S_LEN;

    bf16x8 qa[2];
    {
        const short* qp = Qb + ((size_t)b * S_LEN + qt * 16 + ln) * 64 + g * 8;
        qa[0] = *(const bf16x8*)(qp);
        qa[1] = *(const bf16x8*)(qp + 32);
    }

    f32x4 oacc[4];
#pragma unroll
    for (int i = 0; i < 4; ++i) oacc[i] = (f32x4){0.f, 0.f, 0.f, 0.f};
    float m = -1e30f, l = 0.f;

    char* myp = (char*)smem + w * 2048;             // wave-private 16x64 bf16 P tile (swizzled)
    const float CEXP = 0.18033688011112042f;        // log2(e)/sqrt(64)

    const short* kp = Kbase + ((size_t)w * 1024 + ln) * 64 + g * 8;
    const short* vp = Vbase + (size_t)ln * S_LEN + w * 1024 + g * 8;
    int swz = (ln & 7) << 4;

    for (int t = 0; t < 16; ++t) {
        // ---- S^T = K Q^T : sacc[kt] rows = k_local (g*4+r), cols = q (ln)
        f32x4 sacc[4];
#pragma unroll
        for (int i = 0; i < 4; ++i) sacc[i] = (f32x4){0.f, 0.f, 0.f, 0.f};
#pragma unroll
        for (int hh = 0; hh < 2; ++hh) {
#pragma unroll
            for (int kt = 0; kt < 4; ++kt) {
                bf16x8 kb = *(const bf16x8*)(kp + (size_t)(t * 64 + kt * 16) * 64 + hh * 32);
                sacc[kt] = __builtin_amdgcn_mfma_f32_16x16x32_bf16(kb, qa[hh], sacc[kt], 0, 0, 0);
            }
        }

        // ---- online softmax: each lane owns q=ln, 16 of 64 k-values
        float mx = sacc[0][0];
#pragma unroll
        for (int kt = 0; kt < 4; ++kt)
#pragma unroll
            for (int r = 0; r < 4; ++r) mx = fmaxf(mx, sacc[kt][r]);
        mx = fmaxf(mx, __shfl_xor(mx, 16));
        mx = fmaxf(mx, __shfl_xor(mx, 32));
        float mn = fmaxf(m, mx);
        float fsc = exp2f((m - mn) * CEXP);
        m = mn;
        float mC = m * CEXP;
        float rs = 0.f;
#pragma unroll
        for (int kt = 0; kt < 4; ++kt) {
            float p0 = exp2f(sacc[kt][0] * CEXP - mC);
            float p1 = exp2f(sacc[kt][1] * CEXP - mC);
            float p2 = exp2f(sacc[kt][2] * CEXP - mC);
            float p3 = exp2f(sacc[kt][3] * CEXP - mC);
            rs += (p0 + p1) + (p2 + p3);
            uint2 pk;
            pk.x = cvt_pk(p0, p1);
            pk.y = cvt_pk(p2, p3);
            *(uint2*)(myp + ln * 128 + ((kt * 32 + g * 8) ^ swz)) = pk;
        }
        rs += __shfl_xor(rs, 16);
        rs += __shfl_xor(rs, 32);
        l = l * fsc + rs;
        float fr[4];
#pragma unroll
        for (int r = 0; r < 4; ++r) fr[r] = __shfl(fsc, g * 4 + r);
#pragma unroll
        for (int nt = 0; nt < 4; ++nt)
#pragma unroll
            for (int r = 0; r < 4; ++r) oacc[nt][r] *= fr[r];

        asm volatile("s_waitcnt lgkmcnt(0)" ::: "memory");

        // ---- P A-frags from LDS (row=q=ln, k = kk*32 + g*8 ..)
        bf16x8 pa0 = *(const bf16x8*)(myp + ln * 128 + ((0 + g * 16) ^ swz));
        bf16x8 pa1 = *(const bf16x8*)(myp + ln * 128 + ((64 + g * 16) ^ swz));

        // ---- O += P V
#pragma unroll
        for (int nt = 0; nt < 4; ++nt) {
            bf16x8 vb0 = *(const bf16x8*)(vp + (size_t)(nt * 16) * S_LEN + t * 64);
            bf16x8 vb1 = *(const bf16x8*)(vp + (size_t)(nt * 16) * S_LEN + t * 64 + 32);
            oacc[nt] = __builtin_amdgcn_mfma_f32_16x16x32_bf16(pa0, vb0, oacc[nt], 0, 0, 0);
            oacc[nt] = __builtin_amdgcn_mfma_f32_16x16x32_bf16(pa1, vb1, oacc[nt], 0, 0, 0);
        }
    }

    // ---- stage partials (unnormalized O + raw m, l)
    __syncthreads();
    {
        float* ow = smem + w * 1088;                // [16 q][68] padded rows
#pragma unroll
        for (int nt = 0; nt < 4; ++nt)
#pragma unroll
            for (int r = 0; r < 4; ++r)
                ow[(g * 4 + r) * 68 + nt * 16 + ln] = oacc[nt][r];
        float* ml = smem + 4352;
        if (lane < 16) {
            ml[(w * 16 + ln) * 2] = m;
            ml[(w * 16 + ln) * 2 + 1] = l;
        }
    }
    __syncthreads();

    // ---- merge 4 partials: thread t handles (q = t>>4, h = (t&15)*4 ..+3)
    {
        int tid = threadIdx.x;
        int q = tid >> 4, hb = (tid & 15) * 4;
        const float* ml = smem + 4352;
        float mw[4], lw[4];
#pragma unroll
        for (int w2 = 0; w2 < 4; ++w2) {
            mw[w2] = ml[(w2 * 16 + q) * 2];
            lw[w2] = ml[(w2 * 16 + q) * 2 + 1];
        }
        float M = fmaxf(fmaxf(mw[0], mw[1]), fmaxf(mw[2], mw[3]));
        f32x4 osum = (f32x4){0.f, 0.f, 0.f, 0.f};
        float lsum = 0.f;
#pragma unroll
        for (int w2 = 0; w2 < 4; ++w2) {
            float a = exp2f((mw[w2] - M) * CEXP);
            f32x4 o = *(const f32x4*)(smem + w2 * 1088 + q * 68 + hb);
#pragma unroll
            for (int j = 0; j < 4; ++j) osum[j] += a * o[j];
            lsum += a * lw[w2];
        }
        float inv = 1.f / lsum;
        f32x4 res;
#pragma unroll
        for (int j = 0; j < 4; ++j) res[j] = osum[j] * inv;
        *(f32x4*)(out + ((size_t)b * S_LEN + qt * 16 + q) * 64 + hb) = res;
    }
}

extern "C" void kernel_launch(void* const* d_in, const int* in_sizes, int n_in,
                              void* d_out, int out_size, void* d_ws, size_t ws_size,
                              hipStream_t stream) {
    const float* x  = (const float*)d_in[0];
    const float* Wq = (const float*)d_in[1];
    const float* bq = (const float*)d_in[2];
    const float* Wk = (const float*)d_in[3];
    const float* bk = (const float*)d_in[4];
    const float* Wv = (const float*)d_in[5];
    const float* bv = (const float*)d_in[6];

    short* ws = (short*)d_ws;
    short* Wt = ws;                       // 192*1024
    short* Qb = Wt + 192 * 1024;          // 16384*64
    short* Kb = Qb + 16384 * 64;
    short* Vt = Kb + 16384 * 64;          // [4][64][4096] transposed

    prep_w<<<768, 256, 0, stream>>>(Wq, Wk, Wv, Wt);
    proj_kernel<<<512, 512, 0, stream>>>(x, Wt, bq, bk, bv, Qb, Kb, Vt);
    attn_kernel<<<1024, 256, 0, stream>>>(Qb, Kb, Vt, (float*)d_out);
}

// Round 4
// 124.055 us; speedup vs baseline: 2.3923x; 1.4589x over previous
//
#include <hip/hip_runtime.h>
#include <hip/hip_bf16.h>

// B=4, S=4096, D=1024, H=64 single attention head.
// inputs fp32: x[4,4096,1024], Wq[1024,64], bq[64], Wk, bk, Wv, bv
// output fp32: [4,4096,64]

#define S_LEN 4096
#define D_MODEL 1024

typedef __attribute__((ext_vector_type(8))) short bf16x8;
typedef __attribute__((ext_vector_type(4))) float f32x4;
typedef __attribute__((ext_vector_type(16))) float f32x16;

__device__ inline short f2bf(float f) {
    union { float f; unsigned u; } v;
    v.f = f;
    unsigned r = v.u + 0x7fffu + ((v.u >> 16) & 1u);  // RNE
    return (short)(r >> 16);
}

__device__ inline unsigned cvt_pk(float lo, float hi) {
    unsigned r;
    asm("v_cvt_pk_bf16_f32 %0, %1, %2" : "=v"(r) : "v"(lo), "v"(hi));
    return r;
}

// v_permlane32_swap_b32 a, b:  a' = [a.lo | b.lo-from-other-half], b' = [a.hi-from-other-half | b.hi]
// (semantics per m214's refcheck'd usage: after pl32swap(D0,D2): D0=word0, D2=word2)
__device__ inline void pl32swap(unsigned& a, unsigned& b) {
    asm("v_permlane32_swap_b32 %0, %1" : "+v"(a), "+v"(b));
}

__device__ inline f32x16 fzero16() {
    f32x16 z;
#pragma unroll
    for (int i = 0; i < 16; ++i) z[i] = 0.f;
    return z;
}

// ---------------- kernel 1: W -> Wt bf16 [192][1024] (transposed, concat Q|K|V)
__global__ void prep_w(const float* __restrict__ Wq, const float* __restrict__ Wk,
                       const float* __restrict__ Wv, short* __restrict__ Wt) {
    int idx = blockIdx.x * 256 + threadIdx.x;
    int n = idx >> 10;
    int k = idx & 1023;
    const float* W = (n < 64) ? Wq : (n < 128 ? Wk : Wv);
    int h = n & 63;
    Wt[idx] = f2bf(W[k * 64 + h]);
}

// ---------------- kernel 2: QKV projection, 4-way split-K
// grid 512 x 512 threads (8 waves): wave (rt = w&1 row-tile of 16, ks = w>>1 K-chunk of 256)
__launch_bounds__(512, 4)
__global__ void proj_kernel(const float* __restrict__ x, const short* __restrict__ Wt,
                            const float* __restrict__ bq, const float* __restrict__ bk,
                            const float* __restrict__ bv,
                            short* __restrict__ Qb, short* __restrict__ Kb,
                            short* __restrict__ Vt) {
    __shared__ float psm[6 * 3264];                 // 76.5 KB staging; vsm aliases front
    int w = threadIdx.x >> 6;
    int lane = threadIdx.x & 63;
    int g = lane >> 4, ln = lane & 15;
    int rt = w & 1, ks = w >> 1;
    int rowbase = blockIdx.x * 32 + rt * 16;

    f32x4 acc[12];
#pragma unroll
    for (int i = 0; i < 12; ++i) acc[i] = (f32x4){0.f, 0.f, 0.f, 0.f};

    const float* xp = x + (size_t)(rowbase + ln) * D_MODEL + ks * 256 + g * 8;
    const short* wp = Wt + (size_t)ln * D_MODEL + ks * 256 + g * 8;

#pragma unroll 2
    for (int kk = 0; kk < 8; ++kk) {
        f32x4 a0 = *(const f32x4*)(xp + kk * 32);
        f32x4 a1 = *(const f32x4*)(xp + kk * 32 + 4);
        union { bf16x8 v; unsigned u[4]; } A;
        A.u[0] = cvt_pk(a0[0], a0[1]);
        A.u[1] = cvt_pk(a0[2], a0[3]);
        A.u[2] = cvt_pk(a1[0], a1[1]);
        A.u[3] = cvt_pk(a1[2], a1[3]);
#pragma unroll
        for (int nt = 0; nt < 12; ++nt) {
            bf16x8 bfr = *(const bf16x8*)(wp + (size_t)nt * 16 * D_MODEL + kk * 32);
            acc[nt] = __builtin_amdgcn_mfma_f32_16x16x32_bf16(A.v, bfr, acc[nt], 0, 0, 0);
        }
    }

    if (ks > 0) {
        float* st = psm + ((ks - 1) * 2 + rt) * 3264;
#pragma unroll
        for (int nt = 0; nt < 12; ++nt)
#pragma unroll
            for (int r = 0; r < 4; ++r)
                st[nt * 272 + (g * 4 + r) * 17 + ln] = acc[nt][r];
    }
    __syncthreads();

    short vv[16];                                   // V bf16 values (ks==0 waves only)
    if (ks == 0) {
        const float* s0 = psm + (0 + rt) * 3264;
        const float* s1 = psm + (2 + rt) * 3264;
        const float* s2 = psm + (4 + rt) * 3264;
#pragma unroll
        for (int nt = 0; nt < 12; ++nt) {
            int proj = nt >> 2;
            int h = (nt & 3) * 16 + ln;
            float bias = (proj == 0 ? bq : (proj == 1 ? bk : bv))[h];
#pragma unroll
            for (int r = 0; r < 4; ++r) {
                int idx = nt * 272 + (g * 4 + r) * 17 + ln;
                float v = acc[nt][r] + s0[idx] + s1[idx] + s2[idx] + bias;
                short hv = f2bf(v);
                int srow = rowbase + g * 4 + r;
                if (proj == 0) {
                    Qb[(size_t)srow * 64 + h] = hv;
                } else if (proj == 1) {
                    Kb[(size_t)srow * 64 + h] = hv;
                } else {
                    vv[(nt & 3) * 4 + r] = hv;
                }
            }
        }
    }
    __syncthreads();                                 // psm reads done; safe to alias
    short* vsm = (short*)psm;                        // [64][40] shorts = 5 KB
    if (ks == 0) {
#pragma unroll
        for (int nt = 0; nt < 4; ++nt) {
            int h = nt * 16 + ln;
#pragma unroll
            for (int r = 0; r < 4; ++r)
                vsm[h * 40 + rt * 16 + g * 4 + r] = vv[nt * 4 + r];
        }
    }
    __syncthreads();
    {   // coalesced Vt writeout: 512 threads, thread = (h = t>>3, chunk = t&7 of 4 s)
        int t = threadIdx.x;
        int h = t >> 3, c = t & 7;
        uint2 val = *(const uint2*)(vsm + h * 40 + c * 4);
        int rowbase32 = blockIdx.x * 32;
        int bb = rowbase32 >> 12;
        int sg = (rowbase32 & 4095) + c * 4;
        *(uint2*)(Vt + (((size_t)(bb * 64 + h)) << 12) + sg) = val;
    }
}

// ---------------- kernel 3: flash attention, 32x32 MFMA, all-register softmax/PV
// grid 512 (4 batches x 128 q-tiles of 32) x 256 threads (4 waves = 4-way split-S).
// Wave w: keys [w*1024, (w+1)*1024) in 16 iters of 64. LDS only for final merge.
__launch_bounds__(256)
__global__ void attn_kernel(const short* __restrict__ Qb, const short* __restrict__ Kb,
                            const short* __restrict__ Vt, float* __restrict__ out) {
    __shared__ float osm[4 * 32 * 68];               // per-wave O^T as [q][68]
    __shared__ float mlsm[4 * 32 * 2];
    int lane = threadIdx.x & 63;
    int w = threadIdx.x >> 6;
    int l31 = lane & 31, hi = lane >> 5;
    int b = blockIdx.x >> 7, qt = blockIdx.x & 127;
    size_t qrow = ((size_t)b << 12) + (size_t)qt * 32;

    // Q B-frags: col q = l31, k-dim d = ks*16 + hi*8 + j
    bf16x8 qf[4];
    {
        const short* qp = Qb + (qrow + l31) * 64 + hi * 8;
#pragma unroll
        for (int ks = 0; ks < 4; ++ks) qf[ks] = *(const bf16x8*)(qp + ks * 16);
    }

    f32x16 oacc0 = fzero16(), oacc1 = fzero16();     // O^T[h][q], h-tiles 0,1
    float m = -1e30f, l = 0.f;                       // m in exp2-domain (scaled)
    const float CEXP = 0.18033688011112042f;         // log2(e)/sqrt(64)

    const short* kp = Kb + (((size_t)b << 12) + w * 1024 + l31) * 64 + hi * 8;
    const short* vp = Vt + ((size_t)b * 64 + l31) * S_LEN + w * 1024 + hi * 8;

    for (int t = 0; t < 16; ++t) {
        // K A-frags: row = key (l31 within 32-tile), k-dim d
        bf16x8 kf[8];
        const short* kt0 = kp + (size_t)t * 64 * 64;
#pragma unroll
        for (int kt = 0; kt < 2; ++kt)
#pragma unroll
            for (int ks = 0; ks < 4; ++ks)
                kf[kt * 4 + ks] = *(const bf16x8*)(kt0 + (kt * 32) * 64 + ks * 16);

        f32x16 s0 = fzero16(), s1 = fzero16();       // S^T tiles: row=k_local, col=q
#pragma unroll
        for (int ks = 0; ks < 4; ++ks) {
            s0 = __builtin_amdgcn_mfma_f32_32x32x16_bf16(kf[ks], qf[ks], s0, 0, 0, 0);
            s1 = __builtin_amdgcn_mfma_f32_32x32x16_bf16(kf[4 + ks], qf[ks], s1, 0, 0, 0);
        }

        // V A-frags (issue early): row = h (l31 + ht*32), k-dim = key window kk
        bf16x8 vf[8];
#pragma unroll
        for (int ht = 0; ht < 2; ++ht)
#pragma unroll
            for (int kk = 0; kk < 4; ++kk)
                vf[ht * 4 + kk] = *(const bf16x8*)(vp + (size_t)ht * 32 * S_LEN + t * 64 + kk * 16);

        // ---- online softmax, all in-lane (lane owns 32 k for q = l31)
        float pm = s0[0];
#pragma unroll
        for (int r = 1; r < 16; ++r) pm = fmaxf(pm, s0[r]);
#pragma unroll
        for (int r = 0; r < 16; ++r) pm = fmaxf(pm, s1[r]);
        float pmax = pm * CEXP;
        pmax = fmaxf(pmax, __shfl_xor(pmax, 32));
        if (!__all(pmax <= m + 8.f)) {               // T13 defer-max
            float mn = fmaxf(m, pmax);
            float fsc = exp2f(m - mn);
            m = mn;
            l *= fsc;
#pragma unroll
            for (int r = 0; r < 16; ++r) { oacc0[r] *= fsc; oacc1[r] *= fsc; }
        }

        float rs = 0.f;
#pragma unroll
        for (int kt = 0; kt < 2; ++kt) {
            const f32x16& sv = kt ? s1 : s0;
            float p[16];
#pragma unroll
            for (int r = 0; r < 16; ++r) {
                p[r] = exp2f(sv[r] * CEXP - m);      // <= 2^8
                rs += p[r];
            }
            unsigned D[8];
#pragma unroll
            for (int dw = 0; dw < 8; ++dw) D[dw] = cvt_pk(p[2 * dw], p[2 * dw + 1]);
            pl32swap(D[0], D[2]);                    // -> words 0,2 of ki=0 tuple
            pl32swap(D[1], D[3]);                    // -> words 1,3
            pl32swap(D[4], D[6]);                    // -> words 0,2 of ki=1 tuple
            pl32swap(D[5], D[7]);
            union { unsigned u[4]; bf16x8 v; } t0, t1;
            t0.u[0] = D[0]; t0.u[1] = D[1]; t0.u[2] = D[2]; t0.u[3] = D[3];
            t1.u[0] = D[4]; t1.u[1] = D[5]; t1.u[2] = D[6]; t1.u[3] = D[7];
            // PV: key windows kk = kt*2 + {0,1}
            oacc0 = __builtin_amdgcn_mfma_f32_32x32x16_bf16(vf[kt * 2 + 0], t0.v, oacc0, 0, 0, 0);
            oacc1 = __builtin_amdgcn_mfma_f32_32x32x16_bf16(vf[4 + kt * 2 + 0], t0.v, oacc1, 0, 0, 0);
            oacc0 = __builtin_amdgcn_mfma_f32_32x32x16_bf16(vf[kt * 2 + 1], t1.v, oacc0, 0, 0, 0);
            oacc1 = __builtin_amdgcn_mfma_f32_32x32x16_bf16(vf[4 + kt * 2 + 1], t1.v, oacc1, 0, 0, 0);
        }
        rs += __shfl_xor(rs, 32);
        l += rs;
    }

    // ---- stage partials: O^T -> [q][h] layout, plus (m, l)
    {
        float* ow = osm + w * 2176 + l31 * 68;
#pragma unroll
        for (int r = 0; r < 16; ++r) {
            int h = (r & 3) + 8 * (r >> 2) + 4 * hi;
            ow[h] = oacc0[r];
            ow[32 + h] = oacc1[r];
        }
        if (hi == 0) {
            mlsm[(w * 32 + l31) * 2] = m;
            mlsm[(w * 32 + l31) * 2 + 1] = l;
        }
    }
    __syncthreads();

    // ---- merge 4 partials: thread = (q = t>>3, hb = (t&7)*8)
    {
        int tq = threadIdx.x >> 3, hb = (threadIdx.x & 7) * 8;
        float mw[4], lw[4];
#pragma unroll
        for (int w2 = 0; w2 < 4; ++w2) {
            mw[w2] = mlsm[(w2 * 32 + tq) * 2];
            lw[w2] = mlsm[(w2 * 32 + tq) * 2 + 1];
        }
        float M = fmaxf(fmaxf(mw[0], mw[1]), fmaxf(mw[2], mw[3]));
        f32x4 oa = (f32x4){0.f, 0.f, 0.f, 0.f}, ob = (f32x4){0.f, 0.f, 0.f, 0.f};
        float lsum = 0.f;
#pragma unroll
        for (int w2 = 0; w2 < 4; ++w2) {
            float a = exp2f(mw[w2] - M);
            lsum += a * lw[w2];
            const float* src = osm + w2 * 2176 + tq * 68 + hb;
            f32x4 x0 = *(const f32x4*)src;
            f32x4 x1 = *(const f32x4*)(src + 4);
#pragma unroll
            for (int j = 0; j < 4; ++j) { oa[j] += a * x0[j]; ob[j] += a * x1[j]; }
        }
        float inv = 1.f / lsum;
        f32x4 r0, r1;
#pragma unroll
        for (int j = 0; j < 4; ++j) { r0[j] = oa[j] * inv; r1[j] = ob[j] * inv; }
        float* op = out + (qrow + tq) * 64 + hb;
        *(f32x4*)op = r0;
        *(f32x4*)(op + 4) = r1;
    }
}

extern "C" void kernel_launch(void* const* d_in, const int* in_sizes, int n_in,
                              void* d_out, int out_size, void* d_ws, size_t ws_size,
                              hipStream_t stream) {
    const float* x  = (const float*)d_in[0];
    const float* Wq = (const float*)d_in[1];
    const float* bq = (const float*)d_in[2];
    const float* Wk = (const float*)d_in[3];
    const float* bk = (const float*)d_in[4];
    const float* Wv = (const float*)d_in[5];
    const float* bv = (const float*)d_in[6];

    short* ws = (short*)d_ws;
    short* Wt = ws;                       // 192*1024
    short* Qb = Wt + 192 * 1024;          // 16384*64
    short* Kb = Qb + 16384 * 64;
    short* Vt = Kb + 16384 * 64;          // [4][64][4096] transposed

    prep_w<<<768, 256, 0, stream>>>(Wq, Wk, Wv, Wt);
    proj_kernel<<<512, 512, 0, stream>>>(x, Wt, bq, bk, bv, Qb, Kb, Vt);
    attn_kernel<<<512, 256, 0, stream>>>(Qb, Kb, Vt, (float*)d_out);
}